// Round 1
// baseline (40.689 us; speedup 1.0000x reference)
//
#include <hip/hip_runtime.h>
#include <math.h>

#define Bsz 8
#define Hh 128
#define Ww 128
#define NC 9
#define NP 9
#define OC 8
#define BLOCKS_PER_BATCH 32
#define THREADS 256
#define ACC_PER (OC * NP * 5)   // 360 accumulators per (batch-slice)

// Kernel 1: per-block partial sums of R (3 unique symmetric entries) and q (2)
// per (class, point), accumulated into per-wave LDS f32 buckets.
__global__ __launch_bounds__(THREADS) void cls_vote_partial(
    const float* __restrict__ seg, const float* __restrict__ direct,
    const float* __restrict__ wts, float* __restrict__ partial)
{
    __shared__ float acc[4][ACC_PER];
    const int b = blockIdx.y;
    const int tid = threadIdx.x;
    const int wave = tid >> 6;

    for (int i = tid; i < 4 * ACC_PER; i += THREADS) ((float*)acc)[i] = 0.f;
    __syncthreads();

    const int pixels_per_batch = Hh * Ww;  // 16384
    for (int pid = blockIdx.x * THREADS + tid; pid < pixels_per_batch;
         pid += BLOCKS_PER_BATCH * THREADS) {
        const int h = pid >> 7;    // pid / 128
        const int x = pid & 127;   // pid % 128
        const long base = (long)b * pixels_per_batch + pid;
        const float* s = seg + base * NC;

        // hard argmax over 9 classes (BETA=1e6 softmax ~ one-hot)
        float m = s[0];
        int am = 0;
#pragma unroll
        for (int c = 1; c < NC; ++c) {
            float v = s[c];
            if (v > m) { m = v; am = c; }
        }
        if (am == 0) continue;  // background dropped
        const int cls = am - 1;

        const float ch = (h + 0.5f) * (1.0f / 128.0f);
        const float cw = (x + 0.5f) * (1.0f / 128.0f);
        const float* d = direct + base * (NP * 2);
        const float* wv = wts + base * NP;
        float* a = acc[wave] + cls * (NP * 5);

#pragma unroll
        for (int p = 0; p < NP; ++p) {
            float wx = wv[p];
            float sp = (wx > 20.f) ? wx : log1pf(expf(wx));  // softplus
            float nx = d[2 * p], ny = d[2 * p + 1];
            float nn = nx * nx + ny * ny;
            float R00, R01, R11;
            if (nn > 0.f) {
                float inv = 1.f / nn;
                R00 = sp * (1.f - nx * nx * inv);
                R01 = -sp * (nx * ny * inv);
                R11 = sp * (1.f - ny * ny * inv);
            } else {  // divide_no_nan: n = 0 -> R = w * I
                R00 = sp; R01 = 0.f; R11 = sp;
            }
            float q0 = R00 * ch + R01 * cw;
            float q1 = R01 * ch + R11 * cw;
            atomicAdd(&a[p * 5 + 0], R00);
            atomicAdd(&a[p * 5 + 1], R01);
            atomicAdd(&a[p * 5 + 2], R11);
            atomicAdd(&a[p * 5 + 3], q0);
            atomicAdd(&a[p * 5 + 4], q1);
        }
    }
    __syncthreads();

    float* out = partial + (long)(b * BLOCKS_PER_BATCH + blockIdx.x) * ACC_PER;
    for (int i = tid; i < ACC_PER; i += THREADS)
        out[i] = acc[0][i] + acc[1][i] + acc[2][i] + acc[3][i];
}

// Kernel 2: reduce block partials in f64, 2x2 pinv-solve, scale by HEIGHT.
__global__ void cls_vote_solve(const float* __restrict__ partial,
                               float* __restrict__ out)
{
    int t = blockIdx.x * blockDim.x + threadIdx.x;
    if (t >= Bsz * OC * NP) return;
    int b = t / (OC * NP);
    int r = t % (OC * NP);  // r = cls*NP + p

    double a = 0, bb = 0, c = 0, q0 = 0, q1 = 0;
    const float* base = partial + (long)b * BLOCKS_PER_BATCH * ACC_PER + r * 5;
#pragma unroll 4
    for (int blk = 0; blk < BLOCKS_PER_BATCH; ++blk) {
        const float* pp = base + (long)blk * ACC_PER;
        a  += (double)pp[0];
        bb += (double)pp[1];
        c  += (double)pp[2];
        q0 += (double)pp[3];
        q1 += (double)pp[4];
    }

    double det = a * c - bb * bb;
    double p0 = 0.0, p1 = 0.0;
    if (det != 0.0) {
        double ia = c / det, ib = -bb / det, ic = a / det;
        p0 = ia * q0 + ib * q1;
        p1 = ib * q0 + ic * q1;
    }
    out[2 * t + 0] = (float)(p0 * 128.0);
    out[2 * t + 1] = (float)(p1 * 128.0);
}

extern "C" void kernel_launch(void* const* d_in, const int* in_sizes, int n_in,
                              void* d_out, int out_size, void* d_ws, size_t ws_size,
                              hipStream_t stream) {
    const float* seg    = (const float*)d_in[0];
    const float* direct = (const float*)d_in[1];
    const float* wts    = (const float*)d_in[2];
    float* out = (float*)d_out;
    float* partial = (float*)d_ws;  // Bsz*BLOCKS_PER_BATCH*ACC_PER floats = 368640 B

    dim3 grid1(BLOCKS_PER_BATCH, Bsz);
    cls_vote_partial<<<grid1, THREADS, 0, stream>>>(seg, direct, wts, partial);

    int total = Bsz * OC * NP;  // 576
    cls_vote_solve<<<(total + 255) / 256, 256, 0, stream>>>(partial, out);
}

// Round 3
// 39.231 us; speedup vs baseline: 1.0372x; 1.0372x over previous
//
#include <hip/hip_runtime.h>
#include <math.h>

#define Bsz 8
#define NP 9
#define OC 8
#define TILE 256          // pixels per block
#define BPB 64            // blocks per batch = 16384 / TILE
#define THREADS 256
#define ACC_PER (OC * NP * 5)   // 360 accumulators
#define NCOPY 16                // accumulator replicas (4 waves x 4 lane-groups)

// Kernel 1: stage pixel chunk to LDS via float4, compute per-pixel R/q,
// scatter-add into 16-way replicated LDS accumulators, write block partial.
__global__ __launch_bounds__(THREADS) void cls_vote_partial(
    const float* __restrict__ seg, const float* __restrict__ direct,
    const float* __restrict__ wts, float* __restrict__ partial)
{
    __shared__ float ls_seg[TILE * 9];    //  9216 B (576 float4)
    __shared__ float ls_dir[TILE * 18];   // 18432 B (1152 float4)
    __shared__ float ls_w[TILE * 9];      //  9216 B (576 float4)
    __shared__ float acc[NCOPY][ACC_PER]; // 23040 B   (total 59904 B -> 2 blk/CU)

    const int b = blockIdx.y;
    const int tid = threadIdx.x;
    const int blkpix = blockIdx.x * TILE;
    const long gbase = (long)b * 16384 + blkpix;

    // zero accumulators
    for (int i = tid; i < NCOPY * ACC_PER; i += THREADS) ((float*)acc)[i] = 0.f;

    // coalesced float4 staging (bases are multiples of 2304/4608 floats -> 16B aligned)
    {
        const float4* gs = (const float4*)(seg + gbase * 9);     // 576 float4
        const float4* gd = (const float4*)(direct + gbase * 18); // 1152 float4
        const float4* gw = (const float4*)(wts + gbase * 9);     // 576 float4
        float4* s4 = (float4*)ls_seg;
        float4* d4 = (float4*)ls_dir;
        float4* w4 = (float4*)ls_w;
#pragma unroll
        for (int k = 0; k < 2; ++k) s4[tid + k * THREADS] = gs[tid + k * THREADS];
        if (tid < 64) s4[tid + 512] = gs[tid + 512];             // 512..575
#pragma unroll
        for (int k = 0; k < 4; ++k) d4[tid + k * THREADS] = gd[tid + k * THREADS];
        if (tid < 128) d4[tid + 1024] = gd[tid + 1024];          // 1024..1151
#pragma unroll
        for (int k = 0; k < 2; ++k) w4[tid + k * THREADS] = gw[tid + k * THREADS];
        if (tid < 64) w4[tid + 512] = gw[tid + 512];             // 512..575
    }
    __syncthreads();

    // compute phase: one pixel per thread
    {
        const int pix = tid;
        const int h = (blkpix + pix) >> 7;
        const int x = (blkpix + pix) & 127;
        const float* s = ls_seg + pix * 9;

        float m = s[0];
        int am = 0;
#pragma unroll
        for (int c = 1; c < 9; ++c) {
            float v = s[c];
            if (v > m) { m = v; am = c; }
        }
        if (am != 0) {
            const int cls = am - 1;
            float* a = acc[((tid >> 6) << 2) | (tid & 3)] + cls * (NP * 5);
            const float ch = (h + 0.5f) * 0.0078125f;
            const float cw = (x + 0.5f) * 0.0078125f;
            const float* dd = ls_dir + pix * 18;
            const float* wv = ls_w + pix * 9;
#pragma unroll
            for (int p = 0; p < NP; ++p) {
                float wx = wv[p];
                float e = __expf(wx);
                float sp = (wx > 15.f) ? wx : __logf(1.f + e);
                float nx = dd[2 * p], ny = dd[2 * p + 1];
                float nn = nx * nx + ny * ny;
                float R00, R01, R11;
                if (nn > 0.f) {
                    float inv = __builtin_amdgcn_rcpf(nn);
                    R00 = sp * (1.f - nx * nx * inv);
                    R01 = -sp * (nx * ny * inv);
                    R11 = sp * (1.f - ny * ny * inv);
                } else {  // divide_no_nan: n == 0 -> R = w * I
                    R00 = sp; R01 = 0.f; R11 = sp;
                }
                float q0 = R00 * ch + R01 * cw;
                float q1 = R01 * ch + R11 * cw;
                atomicAdd(&a[p * 5 + 0], R00);
                atomicAdd(&a[p * 5 + 1], R01);
                atomicAdd(&a[p * 5 + 2], R11);
                atomicAdd(&a[p * 5 + 3], q0);
                atomicAdd(&a[p * 5 + 4], q1);
            }
        }
    }
    __syncthreads();

    // reduce 16 copies -> block partial
    float* outp = partial + (long)(b * BPB + blockIdx.x) * ACC_PER;
    for (int i = tid; i < ACC_PER; i += THREADS) {
        float sv = 0.f;
#pragma unroll
        for (int k = 0; k < NCOPY; ++k) sv += acc[k][i];
        outp[i] = sv;
    }
}

// Kernel 2: 4 lanes per (b,cls,p) sum 64 block partials in f64,
// butterfly-reduce, 2x2 solve, scale by HEIGHT=128.
__global__ void cls_vote_solve(const float* __restrict__ partial,
                               float* __restrict__ out)
{
    int t = blockIdx.x * blockDim.x + threadIdx.x;
    if (t >= Bsz * OC * NP * 4) return;
    const int g = t & 3;
    const int id = t >> 2;          // (b, cls*9+p)
    const int b = id / (OC * NP);
    const int r = id % (OC * NP);

    double a = 0, bb = 0, c = 0, q0 = 0, q1 = 0;
    const float* base = partial + (long)b * BPB * ACC_PER + r * 5;
#pragma unroll 4
    for (int blk = g; blk < BPB; blk += 4) {
        const float* pp = base + blk * ACC_PER;
        a  += (double)pp[0];
        bb += (double)pp[1];
        c  += (double)pp[2];
        q0 += (double)pp[3];
        q1 += (double)pp[4];
    }
#pragma unroll
    for (int off = 1; off < 4; off <<= 1) {
        a  += __shfl_xor(a, off, 64);
        bb += __shfl_xor(bb, off, 64);
        c  += __shfl_xor(c, off, 64);
        q0 += __shfl_xor(q0, off, 64);
        q1 += __shfl_xor(q1, off, 64);
    }
    if (g == 0) {
        double det = a * c - bb * bb;
        double p0 = 0.0, p1 = 0.0;
        if (det != 0.0) {
            double ia = c / det, ib = -bb / det, ic = a / det;
            p0 = ia * q0 + ib * q1;
            p1 = ib * q0 + ic * q1;
        }
        out[2 * id + 0] = (float)(p0 * 128.0);
        out[2 * id + 1] = (float)(p1 * 128.0);
    }
}

extern "C" void kernel_launch(void* const* d_in, const int* in_sizes, int n_in,
                              void* d_out, int out_size, void* d_ws, size_t ws_size,
                              hipStream_t stream) {
    const float* seg    = (const float*)d_in[0];
    const float* direct = (const float*)d_in[1];
    const float* wts    = (const float*)d_in[2];
    float* out = (float*)d_out;
    float* partial = (float*)d_ws;  // 8*64*360*4 = 737,280 B

    dim3 grid1(BPB, Bsz);
    cls_vote_partial<<<grid1, THREADS, 0, stream>>>(seg, direct, wts, partial);

    int total = Bsz * OC * NP * 4;  // 2304
    cls_vote_solve<<<(total + 255) / 256, 256, 0, stream>>>(partial, out);
}